// Round 5
// baseline (1181.738 us; speedup 1.0000x reference)
//
#include <hip/hip_runtime.h>
#include <hip/hip_bf16.h>

#define N_NODES 38332
#define POI_LEN 38333
#define CAT_LEN 400
#define POI_DIM 300
#define CAT_DIM 100
#define N_EDGES (N_NODES * 32)
#define NEG_SLOPE 0.01f
#define N_CHUNKS ((N_NODES + 255) / 256)  // 150
#define PROJ_CHUNK 20
#define B1 ((N_NODES + 127) / 128)        // 300 coarse dst-buckets
#define SPLIT_CHUNK 4096
#define NSPLIT ((N_EDGES + SPLIT_CHUNK - 1) / SPLIT_CHUNK)  // 300
#define PLACE_CAP 8192
#define AGG_NB (N_NODES / 4)              // 9583

// ---------------- CSR build ----------------

__global__ void k_zero(int* __restrict__ cnt, float* __restrict__ h128) {
  int i = blockIdx.x * 256 + threadIdx.x;
  if (i < N_NODES) cnt[i] = 0;
  if (i < 128) h128[i] = 0.f;
}

__global__ void k_count(const int* __restrict__ dst, int* __restrict__ cnt) {
  int e = blockIdx.x * 256 + threadIdx.x;
  if (e < N_EDGES) atomicAdd(&cnt[dst[e]], 1);
}

__global__ __launch_bounds__(256) void k_scan1(const int* __restrict__ cnt,
                                               int* __restrict__ partial,
                                               float* __restrict__ dinv) {
  __shared__ int sb[256];
  int tid = threadIdx.x;
  int i = blockIdx.x * 256 + tid;
  int v = (i < N_NODES) ? cnt[i] : 0;
  if (i < N_NODES) dinv[i] = 1.0f / sqrtf((float)(v + 1));  // deg incl self loop
  sb[tid] = v;
  __syncthreads();
  for (int off = 128; off; off >>= 1) {
    if (tid < off) sb[tid] += sb[tid + off];
    __syncthreads();
  }
  if (tid == 0) partial[blockIdx.x] = sb[0];
}

__global__ __launch_bounds__(256) void k_scan2(int* __restrict__ partial) {
  __shared__ int sb[256];
  int tid = threadIdx.x;
  int v = (tid < N_CHUNKS) ? partial[tid] : 0;
  sb[tid] = v;
  __syncthreads();
  for (int off = 1; off < 256; off <<= 1) {
    int t = (tid >= off) ? sb[tid - off] : 0;
    __syncthreads();
    sb[tid] += t;
    __syncthreads();
  }
  if (tid < N_CHUNKS) partial[tid] = sb[tid] - v;  // exclusive
}

__global__ __launch_bounds__(256) void k_scan3(const int* __restrict__ cnt,
                                               const int* __restrict__ partial,
                                               int* __restrict__ row_start) {
  __shared__ int sb[256];
  int tid = threadIdx.x;
  int i = blockIdx.x * 256 + tid;
  int v = (i < N_NODES) ? cnt[i] : 0;
  sb[tid] = v;
  __syncthreads();
  for (int off = 1; off < 256; off <<= 1) {
    int t = (tid >= off) ? sb[tid - off] : 0;
    __syncthreads();
    sb[tid] += t;
    __syncthreads();
  }
  if (i < N_NODES) row_start[i] = partial[blockIdx.x] + sb[tid] - v;
  if (i == N_NODES - 1) row_start[N_NODES] = partial[blockIdx.x] + sb[tid];
}

__global__ void k_binit(const int* __restrict__ row_start, int* __restrict__ bcur) {
  int b = blockIdx.x * 256 + threadIdx.x;
  if (b < B1) bcur[b] = row_start[b * 128];
}

// Level-1: bucket (src,dst) pairs by dst>>7 into per-bucket contiguous staging
// ranges. Per-(block,bucket) global reservation -> writes from one CU land in
// one short contiguous run (write-combine friendly; no cross-XCD line sharing).
__global__ __launch_bounds__(256) void k_split(const int* __restrict__ src,
                                               const int* __restrict__ dst,
                                               int* __restrict__ bcur,
                                               int2* __restrict__ staging) {
  __shared__ int hist[B1];
  __shared__ int lbase[B1];
  __shared__ int lcur[B1];
  int tid = threadIdx.x;
  int base = blockIdx.x * SPLIT_CHUNK;
  int n = N_EDGES - base;
  if (n > SPLIT_CHUNK) n = SPLIT_CHUNK;
  for (int b = tid; b < B1; b += 256) {
    hist[b] = 0;
    lcur[b] = 0;
  }
  __syncthreads();
  for (int i = tid; i < n; i += 256) atomicAdd(&hist[dst[base + i] >> 7], 1);
  __syncthreads();
  for (int b = tid; b < B1; b += 256) {
    int c = hist[b];
    lbase[b] = c ? atomicAdd(&bcur[b], c) : 0;
  }
  __syncthreads();
  for (int i = tid; i < n; i += 256) {
    int d = dst[base + i];
    int s = src[base + i];
    int b = d >> 7;
    int off = atomicAdd(&lcur[b], 1);
    staging[lbase[b] + off] = make_int2(s, d);
  }
}

// Level-2: one block per bucket; exact per-dst placement in LDS, then a fully
// coalesced copy of the bucket's CSR region to global.
__global__ __launch_bounds__(256) void k_place(const int2* __restrict__ staging,
                                               const int* __restrict__ row_start,
                                               int* __restrict__ csr_src) {
  __shared__ int cur[128];
  __shared__ int buf[PLACE_CAP];
  int b = blockIdx.x;
  int d0 = b * 128;
  int d1 = d0 + 128;
  if (d1 > N_NODES) d1 = N_NODES;
  int tid = threadIdx.x;
  int e0 = row_start[d0];
  int e1 = row_start[d1];
  int cnt = e1 - e0;
  if (tid < d1 - d0) cur[tid] = row_start[d0 + tid] - e0;
  __syncthreads();
  for (int i = tid; i < cnt; i += 256) {
    int2 p = staging[e0 + i];
    int pos = atomicAdd(&cur[p.y - d0], 1);
    if (pos < PLACE_CAP) buf[pos] = p.x;
    else csr_src[e0 + pos] = p.x;  // overflow fallback (statistically never)
  }
  __syncthreads();
  for (int i = tid; i < cnt && i < PLACE_CAP; i += 256) csr_src[e0 + i] = buf[i];
}

// ---------------- projection GEMM: C[M][64] = A[M][K] @ W[K][64] ----------

__global__ __launch_bounds__(256) void k_proj(const float* __restrict__ A,
                                              const float* __restrict__ W,
                                              float* __restrict__ C, int M, int K) {
  __shared__ float sA[16][24];
  int tid = threadIdx.x;
  int lane = tid & 63;
  int wv = tid >> 6;
  int row0 = blockIdx.x * 16;
  float acc[4] = {0.f, 0.f, 0.f, 0.f};

  for (int c = 0; c < K; c += PROJ_CHUNK) {
    __syncthreads();
    for (int idx = tid; idx < 16 * PROJ_CHUNK; idx += 256) {
      int r = idx / PROJ_CHUNK;
      int k = idx % PROJ_CHUNK;
      int row = row0 + r;
      sA[r][k] = (row < M) ? A[(size_t)row * K + c + k] : 0.f;
    }
    __syncthreads();
#pragma unroll
    for (int k4 = 0; k4 < PROJ_CHUNK / 4; k4++) {
      int k = c + k4 * 4;
      float w0 = W[(k + 0) * 64 + lane];
      float w1 = W[(k + 1) * 64 + lane];
      float w2 = W[(k + 2) * 64 + lane];
      float w3 = W[(k + 3) * 64 + lane];
#pragma unroll
      for (int r = 0; r < 4; r++) {
        const float4 f4 = *(const float4*)&sA[wv * 4 + r][k4 * 4];
        acc[r] += f4.x * w0 + f4.y * w1 + f4.z * w2 + f4.w * w3;
      }
    }
  }
#pragma unroll
  for (int r = 0; r < 4; r++) {
    int row = row0 + wv * 4 + r;
    if (row < M) C[(size_t)row * 64 + lane] = acc[r];
  }
}

// ---------------- gather + combine -> sliced hs ----------------
// hs_s layout: [slice][node][16]; channel (slice*16+ch) == original lane.

__global__ __launch_bounds__(256) void k_gather(
    const float* __restrict__ x, const float* __restrict__ proj_poi,
    const float* __restrict__ proj_cat, const float* __restrict__ W_in,
    const float* __restrict__ dinv, float* __restrict__ hs_s) {
  int lane = threadIdx.x & 63;
  int w = threadIdx.x >> 6;
  int node = blockIdx.x * 4 + w;
  int pid = (int)x[node * 5 + 0];
  int cid = (int)x[node * 5 + 1];
  float x2 = x[node * 5 + 2];
  float x3 = x[node * 5 + 3];
  float x4 = x[node * 5 + 4];
  float v = proj_poi[(size_t)pid * 64 + lane] + proj_cat[(size_t)cid * 64 + lane] +
            x2 * W_in[400 * 64 + lane] + x3 * W_in[401 * 64 + lane] +
            x4 * W_in[402 * 64 + lane];
  int slice = lane >> 4, ch = lane & 15;
  hs_s[((size_t)slice * N_NODES + node) * 16 + ch] = v * dinv[node];
}

// ---------------- middle transform: hs_s = (feat @ W) * dinv ----------------

__global__ __launch_bounds__(256) void k_xform(const float* __restrict__ feat,
                                               const float* __restrict__ W,
                                               const float* __restrict__ dinv,
                                               float* __restrict__ hs_s) {
  __shared__ float sW[64 * 64];
  int tid = threadIdx.x;
  int lane = tid & 63;
  int w = tid >> 6;
  for (int k = tid; k < 64 * 64; k += 256) sW[k] = W[k];
  __syncthreads();
  int node = blockIdx.x * 4 + w;
  float f = feat[(size_t)node * 64 + lane];
  float acc = 0.f;
#pragma unroll
  for (int k = 0; k < 64; k++) {
    float fk = __shfl(f, k, 64);
    acc += fk * sW[k * 64 + lane];
  }
  int slice = lane >> 4, ch = lane & 15;
  hs_s[((size_t)slice * N_NODES + node) * 16 + ch] = acc * dinv[node];
}

// ---------------- aggregation, slice-phased ----------------
// grid = 4 slices x 9583 blocks (monotonic dispatch -> one 2.45 MB hs-slice
// live per phase, resident in every XCD's L2). Wave = 1 dst node; lane =
// eslot(4) x ch(16): one load instr gathers 4 edges x 64B lines.

template <int MODE>
__global__ __launch_bounds__(256) void k_agg(const float* __restrict__ hs_s,
                                             const int* __restrict__ row_start,
                                             const int* __restrict__ csr_src,
                                             const float* __restrict__ dinv,
                                             const float* __restrict__ bias,
                                             float* __restrict__ feat) {
  int tid = threadIdx.x;
  int lane = tid & 63;
  int wv = tid >> 6;
  int bid = blockIdx.x;
  int slice = bid / AGG_NB;
  int nb = bid - slice * AGG_NB;
  int node = nb * 4 + wv;
  int ch = lane & 15;
  int eslot = lane >> 4;
  const float* hsl = hs_s + (size_t)slice * N_NODES * 16;
  int r0 = row_start[node];
  int r1 = row_start[node + 1];
  float a0 = 0.f, a1 = 0.f;
  int e = r0 + eslot;
  for (; e + 4 < r1; e += 8) {
    int s0 = __builtin_nontemporal_load(csr_src + e);
    int s1 = __builtin_nontemporal_load(csr_src + e + 4);
    a0 += hsl[(size_t)s0 * 16 + ch];
    a1 += hsl[(size_t)s1 * 16 + ch];
  }
  if (e < r1) {
    int s = __builtin_nontemporal_load(csr_src + e);
    a0 += hsl[(size_t)s * 16 + ch];
  }
  float v = a0 + a1;
  v += __shfl_xor(v, 16, 64);
  v += __shfl_xor(v, 32, 64);
  float self = hsl[(size_t)node * 16 + ch];
  float t = dinv[node] * (v + self) + bias[lane & 15 | (slice << 4)];
  float lt = (t >= 0.f) ? t : NEG_SLOPE * t;
  float o = MODE ? (lt + t) : lt;
  if (lane < 16)
    __builtin_nontemporal_store(o, feat + (size_t)node * 64 + slice * 16 + ch);
}

// ---------------- output head (64 -> 1) ----------------

__global__ __launch_bounds__(256) void k_out_xform(const float* __restrict__ feat,
                                                   const float* __restrict__ W_out,
                                                   const float* __restrict__ dinv,
                                                   float* __restrict__ hs1) {
  int lane = threadIdx.x & 63;
  int w = threadIdx.x >> 6;
  int node = blockIdx.x * 4 + w;
  float v = feat[(size_t)node * 64 + lane] * W_out[lane];
#pragma unroll
  for (int off = 32; off; off >>= 1) v += __shfl_xor(v, off, 64);
  if (lane == 0) hs1[node] = v * dinv[node];
}

__global__ __launch_bounds__(256) void k_out_agg(const float* __restrict__ hs1,
                                                 const int* __restrict__ row_start,
                                                 const int* __restrict__ csr_src,
                                                 const float* __restrict__ dinv,
                                                 const float* __restrict__ b_out,
                                                 float* __restrict__ g) {
  int lane = threadIdx.x & 63;
  int w = threadIdx.x >> 6;
  int node = blockIdx.x * 4 + w;
  int r0 = row_start[node];
  int r1 = row_start[node + 1];
  float acc = 0.f;
  for (int e = r0 + lane; e < r1; e += 64) acc += hs1[csr_src[e]];
#pragma unroll
  for (int off = 32; off; off >>= 1) acc += __shfl_xor(acc, off, 64);
  if (lane == 0) {
    float t = dinv[node] * (acc + hs1[node]) + b_out[0];
    g[node] = (t >= 0.f) ? t : NEG_SLOPE * t;
  }
}

// ---------------- FC head ----------------

__global__ __launch_bounds__(128) void k_fc1(const float* __restrict__ g,
                                             const float* __restrict__ fc1_W,
                                             float* __restrict__ h128) {
  int j = threadIdx.x;  // 0..127
  int base = blockIdx.x * 32;
  int end = base + 32;
  if (end > N_NODES) end = N_NODES;
  float acc = 0.f;
  int i = base;
  for (; i + 4 <= end; i += 4) {
    acc += g[i + 0] * fc1_W[(size_t)(i + 0) * 128 + j];
    acc += g[i + 1] * fc1_W[(size_t)(i + 1) * 128 + j];
    acc += g[i + 2] * fc1_W[(size_t)(i + 2) * 128 + j];
    acc += g[i + 3] * fc1_W[(size_t)(i + 3) * 128 + j];
  }
  for (; i < end; i++) acc += g[i] * fc1_W[(size_t)i * 128 + j];
  atomicAdd(&h128[j], acc);
}

__global__ __launch_bounds__(256) void k_fc2(const float* __restrict__ h128raw,
                                             const float* __restrict__ fc1_b,
                                             const float* __restrict__ fc2_W,
                                             const float* __restrict__ fc2_b,
                                             float* __restrict__ out) {
  __shared__ float sh[128];
  int tid = threadIdx.x;
  if (tid < 128) {
    float v = h128raw[tid] + fc1_b[tid];
    sh[tid] = (v > 0.f) ? v : 0.f;
  }
  __syncthreads();
  int p = blockIdx.x * 256 + tid;
  if (p < POI_LEN) {
    float acc = fc2_b[p];
#pragma unroll 8
    for (int j = 0; j < 128; j++) acc += sh[j] * fc2_W[(size_t)j * POI_LEN + p];
    out[p] = (acc > 0.f) ? acc : 0.f;
  }
}

// ---------------- launch ----------------

extern "C" void kernel_launch(void* const* d_in, const int* in_sizes, int n_in,
                              void* d_out, int out_size, void* d_ws, size_t ws_size,
                              hipStream_t stream) {
  const float* x       = (const float*)d_in[0];
  const int*   ei      = (const int*)d_in[1];
  const float* poi_emb = (const float*)d_in[2];
  const float* cat_emb = (const float*)d_in[3];
  const float* W_in    = (const float*)d_in[4];
  const float* b_in    = (const float*)d_in[5];
  const float* gcn_Ws  = (const float*)d_in[6];
  const float* gcn_bs  = (const float*)d_in[7];
  const float* W_out   = (const float*)d_in[8];
  const float* b_out   = (const float*)d_in[9];
  const float* fc1_W   = (const float*)d_in[10];
  const float* fc1_b   = (const float*)d_in[11];
  const float* fc2_W   = (const float*)d_in[12];
  const float* fc2_b   = (const float*)d_in[13];
  const int* src = ei;
  const int* dst = ei + N_EDGES;

  char* p = (char*)d_ws;
  auto take = [&](size_t bytes) {
    char* r = p;
    p += (bytes + 255) & ~(size_t)255;
    return r;
  };
  int*   cnt       = (int*)take((size_t)N_NODES * 4);
  int*   row_start = (int*)take((size_t)(N_NODES + 1) * 4);
  float* dinv      = (float*)take((size_t)N_NODES * 4);
  int*   bcur      = (int*)take((size_t)B1 * 4);
  int*   csr_src   = (int*)take((size_t)N_EDGES * 4);
  float* feat      = (float*)take((size_t)N_NODES * 64 * 4);
  float* hs_s      = (float*)take((size_t)N_NODES * 64 * 4);
  float* proj_poi  = (float*)take((size_t)POI_LEN * 64 * 4);   // aliased by staging
  float* proj_cat  = (float*)take((size_t)CAT_LEN * 64 * 4);
  float* hs1       = (float*)take((size_t)N_NODES * 4);
  float* g         = (float*)take((size_t)N_NODES * 4);
  float* h128      = (float*)take(128 * 4);
  int*   partial   = (int*)take((size_t)N_CHUNKS * 4);
  int2*  staging   = (int2*)proj_poi;  // POI_LEN*64*4 == N_EDGES*8 + slack: both ~9.81 MB
  float* out       = (float*)d_out;

  const int nb4 = N_NODES / 4;            // 9583
  const int nbE = (N_EDGES + 255) / 256;  // 4792

  k_zero<<<N_CHUNKS, 256, 0, stream>>>(cnt, h128);
  k_count<<<nbE, 256, 0, stream>>>(dst, cnt);
  k_scan1<<<N_CHUNKS, 256, 0, stream>>>(cnt, partial, dinv);
  k_scan2<<<1, 256, 0, stream>>>(partial);
  k_scan3<<<N_CHUNKS, 256, 0, stream>>>(cnt, partial, row_start);
  k_binit<<<(B1 + 255) / 256, 256, 0, stream>>>(row_start, bcur);

  // front-end first (proj_poi's region is reused as scatter staging afterwards)
  k_proj<<<(POI_LEN + 15) / 16, 256, 0, stream>>>(poi_emb, W_in, proj_poi,
                                                  POI_LEN, POI_DIM);
  k_proj<<<(CAT_LEN + 15) / 16, 256, 0, stream>>>(cat_emb, W_in + 300 * 64,
                                                  proj_cat, CAT_LEN, CAT_DIM);
  k_gather<<<nb4, 256, 0, stream>>>(x, proj_poi, proj_cat, W_in, dinv, hs_s);

  // CSR edge placement (two-level, coalesced writes)
  k_split<<<NSPLIT, 256, 0, stream>>>(src, dst, bcur, staging);
  k_place<<<B1, 256, 0, stream>>>(staging, row_start, csr_src);

  k_agg<0><<<4 * nb4, 256, 0, stream>>>(hs_s, row_start, csr_src, dinv, b_in, feat);
  for (int l = 0; l < 5; l++) {
    k_xform<<<nb4, 256, 0, stream>>>(feat, gcn_Ws + (size_t)l * 64 * 64, dinv, hs_s);
    k_agg<1><<<4 * nb4, 256, 0, stream>>>(hs_s, row_start, csr_src, dinv,
                                          gcn_bs + (size_t)l * 64, feat);
  }

  k_out_xform<<<nb4, 256, 0, stream>>>(feat, W_out, dinv, hs1);
  k_out_agg<<<nb4, 256, 0, stream>>>(hs1, row_start, csr_src, dinv, b_out, g);
  k_fc1<<<(N_NODES + 31) / 32, 128, 0, stream>>>(g, fc1_W, h128);
  k_fc2<<<(POI_LEN + 255) / 256, 256, 0, stream>>>(h128, fc1_b, fc2_W, fc2_b, out);
}

// Round 6
// 814.012 us; speedup vs baseline: 1.4517x; 1.4517x over previous
//
#include <hip/hip_runtime.h>
#include <hip/hip_bf16.h>

#define N_NODES 38332
#define POI_LEN 38333
#define CAT_LEN 400
#define POI_DIM 300
#define CAT_DIM 100
#define N_EDGES (N_NODES * 32)
#define NEG_SLOPE 0.01f
#define N_CHUNKS ((N_NODES + 255) / 256)  // 150
#define PROJ_CHUNK 20
#define B1 ((N_NODES + 127) / 128)        // 300 coarse dst-buckets
#define SPLIT_CHUNK 4096
#define NSPLIT ((N_EDGES + SPLIT_CHUNK - 1) / SPLIT_CHUNK)  // 300
#define PLACE_CAP 8192

// ---------------- CSR build ----------------

__global__ void k_zero(int* __restrict__ cnt, float* __restrict__ h128) {
  int i = blockIdx.x * 256 + threadIdx.x;
  if (i < N_NODES) cnt[i] = 0;
  if (i < 128) h128[i] = 0.f;
}

__global__ void k_count(const int* __restrict__ dst, int* __restrict__ cnt) {
  int e = blockIdx.x * 256 + threadIdx.x;
  if (e < N_EDGES) atomicAdd(&cnt[dst[e]], 1);
}

__global__ __launch_bounds__(256) void k_scan1(const int* __restrict__ cnt,
                                               int* __restrict__ partial,
                                               float* __restrict__ dinv) {
  __shared__ int sb[256];
  int tid = threadIdx.x;
  int i = blockIdx.x * 256 + tid;
  int v = (i < N_NODES) ? cnt[i] : 0;
  if (i < N_NODES) dinv[i] = 1.0f / sqrtf((float)(v + 1));  // deg incl self loop
  sb[tid] = v;
  __syncthreads();
  for (int off = 128; off; off >>= 1) {
    if (tid < off) sb[tid] += sb[tid + off];
    __syncthreads();
  }
  if (tid == 0) partial[blockIdx.x] = sb[0];
}

__global__ __launch_bounds__(256) void k_scan2(int* __restrict__ partial) {
  __shared__ int sb[256];
  int tid = threadIdx.x;
  int v = (tid < N_CHUNKS) ? partial[tid] : 0;
  sb[tid] = v;
  __syncthreads();
  for (int off = 1; off < 256; off <<= 1) {
    int t = (tid >= off) ? sb[tid - off] : 0;
    __syncthreads();
    sb[tid] += t;
    __syncthreads();
  }
  if (tid < N_CHUNKS) partial[tid] = sb[tid] - v;  // exclusive
}

__global__ __launch_bounds__(256) void k_scan3(const int* __restrict__ cnt,
                                               const int* __restrict__ partial,
                                               int* __restrict__ row_start) {
  __shared__ int sb[256];
  int tid = threadIdx.x;
  int i = blockIdx.x * 256 + tid;
  int v = (i < N_NODES) ? cnt[i] : 0;
  sb[tid] = v;
  __syncthreads();
  for (int off = 1; off < 256; off <<= 1) {
    int t = (tid >= off) ? sb[tid - off] : 0;
    __syncthreads();
    sb[tid] += t;
    __syncthreads();
  }
  if (i < N_NODES) row_start[i] = partial[blockIdx.x] + sb[tid] - v;
  if (i == N_NODES - 1) row_start[N_NODES] = partial[blockIdx.x] + sb[tid];
}

__global__ void k_binit(const int* __restrict__ row_start, int* __restrict__ bcur) {
  int b = blockIdx.x * 256 + threadIdx.x;
  if (b < B1) bcur[b] = row_start[b * 128];
}

// Level-1: bucket (src,dst) pairs by dst>>7 into per-bucket contiguous staging
// ranges (writes from one CU land in short contiguous runs).
__global__ __launch_bounds__(256) void k_split(const int* __restrict__ src,
                                               const int* __restrict__ dst,
                                               int* __restrict__ bcur,
                                               int2* __restrict__ staging) {
  __shared__ int hist[B1];
  __shared__ int lbase[B1];
  __shared__ int lcur[B1];
  int tid = threadIdx.x;
  int base = blockIdx.x * SPLIT_CHUNK;
  int n = N_EDGES - base;
  if (n > SPLIT_CHUNK) n = SPLIT_CHUNK;
  for (int b = tid; b < B1; b += 256) {
    hist[b] = 0;
    lcur[b] = 0;
  }
  __syncthreads();
  for (int i = tid; i < n; i += 256) atomicAdd(&hist[dst[base + i] >> 7], 1);
  __syncthreads();
  for (int b = tid; b < B1; b += 256) {
    int c = hist[b];
    lbase[b] = c ? atomicAdd(&bcur[b], c) : 0;
  }
  __syncthreads();
  for (int i = tid; i < n; i += 256) {
    int d = dst[base + i];
    int s = src[base + i];
    int b = d >> 7;
    int off = atomicAdd(&lcur[b], 1);
    staging[lbase[b] + off] = make_int2(s, d);
  }
}

// Level-2: one block per bucket; exact per-dst placement in LDS, coalesced copy out.
__global__ __launch_bounds__(256) void k_place(const int2* __restrict__ staging,
                                               const int* __restrict__ row_start,
                                               int* __restrict__ csr_src) {
  __shared__ int cur[128];
  __shared__ int buf[PLACE_CAP];
  int b = blockIdx.x;
  int d0 = b * 128;
  int d1 = d0 + 128;
  if (d1 > N_NODES) d1 = N_NODES;
  int tid = threadIdx.x;
  int e0 = row_start[d0];
  int e1 = row_start[d1];
  int cnt = e1 - e0;
  if (tid < d1 - d0) cur[tid] = row_start[d0 + tid] - e0;
  __syncthreads();
  for (int i = tid; i < cnt; i += 256) {
    int2 p = staging[e0 + i];
    int pos = atomicAdd(&cur[p.y - d0], 1);
    if (pos < PLACE_CAP) buf[pos] = p.x;
    else csr_src[e0 + pos] = p.x;  // overflow fallback (statistically never)
  }
  __syncthreads();
  for (int i = tid; i < cnt && i < PLACE_CAP; i += 256) csr_src[e0 + i] = buf[i];
}

// ---------------- projection GEMM: C[M][64] = A[M][K] @ W[K][64] ----------

__global__ __launch_bounds__(256) void k_proj(const float* __restrict__ A,
                                              const float* __restrict__ W,
                                              float* __restrict__ C, int M, int K) {
  __shared__ float sA[16][24];
  int tid = threadIdx.x;
  int lane = tid & 63;
  int wv = tid >> 6;
  int row0 = blockIdx.x * 16;
  float acc[4] = {0.f, 0.f, 0.f, 0.f};

  for (int c = 0; c < K; c += PROJ_CHUNK) {
    __syncthreads();
    for (int idx = tid; idx < 16 * PROJ_CHUNK; idx += 256) {
      int r = idx / PROJ_CHUNK;
      int k = idx % PROJ_CHUNK;
      int row = row0 + r;
      sA[r][k] = (row < M) ? A[(size_t)row * K + c + k] : 0.f;
    }
    __syncthreads();
#pragma unroll
    for (int k4 = 0; k4 < PROJ_CHUNK / 4; k4++) {
      int k = c + k4 * 4;
      float w0 = W[(k + 0) * 64 + lane];
      float w1 = W[(k + 1) * 64 + lane];
      float w2 = W[(k + 2) * 64 + lane];
      float w3 = W[(k + 3) * 64 + lane];
#pragma unroll
      for (int r = 0; r < 4; r++) {
        const float4 f4 = *(const float4*)&sA[wv * 4 + r][k4 * 4];
        acc[r] += f4.x * w0 + f4.y * w1 + f4.z * w2 + f4.w * w3;
      }
    }
  }
#pragma unroll
  for (int r = 0; r < 4; r++) {
    int row = row0 + wv * 4 + r;
    if (row < M) C[(size_t)row * 64 + lane] = acc[r];
  }
}

// ---------------- gather + combine -> flat hs ----------------

__global__ __launch_bounds__(256) void k_gather(
    const float* __restrict__ x, const float* __restrict__ proj_poi,
    const float* __restrict__ proj_cat, const float* __restrict__ W_in,
    const float* __restrict__ dinv, float* __restrict__ hs) {
  int lane = threadIdx.x & 63;
  int w = threadIdx.x >> 6;
  int node = blockIdx.x * 4 + w;
  int pid = (int)x[node * 5 + 0];
  int cid = (int)x[node * 5 + 1];
  float x2 = x[node * 5 + 2];
  float x3 = x[node * 5 + 3];
  float x4 = x[node * 5 + 4];
  float v = proj_poi[(size_t)pid * 64 + lane] + proj_cat[(size_t)cid * 64 + lane] +
            x2 * W_in[400 * 64 + lane] + x3 * W_in[401 * 64 + lane] +
            x4 * W_in[402 * 64 + lane];
  hs[(size_t)node * 64 + lane] = v * dinv[node];
}

// ---------------- middle transform: hs = (feat @ W) * dinv ----------------

__global__ __launch_bounds__(256) void k_xform(const float* __restrict__ feat,
                                               const float* __restrict__ W,
                                               const float* __restrict__ dinv,
                                               float* __restrict__ hs) {
  __shared__ float sW[64 * 64];
  int tid = threadIdx.x;
  int lane = tid & 63;
  int w = tid >> 6;
  for (int k = tid; k < 64 * 64; k += 256) sW[k] = W[k];
  __syncthreads();
  int node = blockIdx.x * 4 + w;
  float f = feat[(size_t)node * 64 + lane];
  float acc = 0.f;
#pragma unroll
  for (int k = 0; k < 64; k++) {
    float fk = __shfl(f, k, 64);
    acc += fk * sW[k * 64 + lane];
  }
  hs[(size_t)node * 64 + lane] = acc * dinv[node];
}

// ---------------- aggregation, float4-lane / max-MLP ----------------
// wave = 1 dst node. lane = eslot(4) x ch16(16); each lane loads float4:
// one gather instr covers 4 edges x 256B rows = 16 lines in flight; 4
// independent accumulators -> up to 64 lines outstanding per wave.

template <int MODE>
__global__ __launch_bounds__(256) void k_agg(const float* __restrict__ hs,
                                             const int* __restrict__ row_start,
                                             const int* __restrict__ csr_src,
                                             const float* __restrict__ dinv,
                                             const float* __restrict__ bias,
                                             float* __restrict__ feat) {
  int tid = threadIdx.x;
  int lane = tid & 63;
  int wv = tid >> 6;
  int node = blockIdx.x * 4 + wv;
  int eslot = lane >> 4;    // 0..3
  int ch16 = lane & 15;     // float4 slot within 64-ch row
  int r0 = row_start[node];
  int r1 = row_start[node + 1];
  float4 a0 = {0.f, 0.f, 0.f, 0.f}, a1 = a0, a2 = a0, a3 = a0;
  int e = r0 + eslot;
  for (; e + 12 < r1; e += 16) {
    int s0 = csr_src[e];
    int s1 = csr_src[e + 4];
    int s2 = csr_src[e + 8];
    int s3 = csr_src[e + 12];
    float4 v0 = *(const float4*)(hs + (size_t)s0 * 64 + ch16 * 4);
    float4 v1 = *(const float4*)(hs + (size_t)s1 * 64 + ch16 * 4);
    float4 v2 = *(const float4*)(hs + (size_t)s2 * 64 + ch16 * 4);
    float4 v3 = *(const float4*)(hs + (size_t)s3 * 64 + ch16 * 4);
    a0.x += v0.x; a0.y += v0.y; a0.z += v0.z; a0.w += v0.w;
    a1.x += v1.x; a1.y += v1.y; a1.z += v1.z; a1.w += v1.w;
    a2.x += v2.x; a2.y += v2.y; a2.z += v2.z; a2.w += v2.w;
    a3.x += v3.x; a3.y += v3.y; a3.z += v3.z; a3.w += v3.w;
  }
  for (; e < r1; e += 4) {
    int s = csr_src[e];
    float4 v = *(const float4*)(hs + (size_t)s * 64 + ch16 * 4);
    a0.x += v.x; a0.y += v.y; a0.z += v.z; a0.w += v.w;
  }
  float4 v;
  v.x = (a0.x + a1.x) + (a2.x + a3.x);
  v.y = (a0.y + a1.y) + (a2.y + a3.y);
  v.z = (a0.z + a1.z) + (a2.z + a3.z);
  v.w = (a0.w + a1.w) + (a2.w + a3.w);
  // reduce over the 4 eslots (lanes ch16, ch16+16, ch16+32, ch16+48)
#pragma unroll
  for (int off = 16; off <= 32; off <<= 1) {
    v.x += __shfl_xor(v.x, off, 64);
    v.y += __shfl_xor(v.y, off, 64);
    v.z += __shfl_xor(v.z, off, 64);
    v.w += __shfl_xor(v.w, off, 64);
  }
  if (lane < 16) {
    float4 self = *(const float4*)(hs + (size_t)node * 64 + ch16 * 4);
    float4 bb = *(const float4*)(bias + ch16 * 4);
    float dn = dinv[node];
    float4 t, o;
    t.x = dn * (v.x + self.x) + bb.x;
    t.y = dn * (v.y + self.y) + bb.y;
    t.z = dn * (v.z + self.z) + bb.z;
    t.w = dn * (v.w + self.w) + bb.w;
    float4 lt;
    lt.x = (t.x >= 0.f) ? t.x : NEG_SLOPE * t.x;
    lt.y = (t.y >= 0.f) ? t.y : NEG_SLOPE * t.y;
    lt.z = (t.z >= 0.f) ? t.z : NEG_SLOPE * t.z;
    lt.w = (t.w >= 0.f) ? t.w : NEG_SLOPE * t.w;
    if (MODE) {
      o.x = lt.x + t.x; o.y = lt.y + t.y; o.z = lt.z + t.z; o.w = lt.w + t.w;
    } else {
      o = lt;
    }
    *(float4*)(feat + (size_t)node * 64 + ch16 * 4) = o;
  }
}

// ---------------- output head (64 -> 1) ----------------

__global__ __launch_bounds__(256) void k_out_xform(const float* __restrict__ feat,
                                                   const float* __restrict__ W_out,
                                                   const float* __restrict__ dinv,
                                                   float* __restrict__ hs1) {
  int lane = threadIdx.x & 63;
  int w = threadIdx.x >> 6;
  int node = blockIdx.x * 4 + w;
  float v = feat[(size_t)node * 64 + lane] * W_out[lane];
#pragma unroll
  for (int off = 32; off; off >>= 1) v += __shfl_xor(v, off, 64);
  if (lane == 0) hs1[node] = v * dinv[node];
}

__global__ __launch_bounds__(256) void k_out_agg(const float* __restrict__ hs1,
                                                 const int* __restrict__ row_start,
                                                 const int* __restrict__ csr_src,
                                                 const float* __restrict__ dinv,
                                                 const float* __restrict__ b_out,
                                                 float* __restrict__ g) {
  int lane = threadIdx.x & 63;
  int w = threadIdx.x >> 6;
  int node = blockIdx.x * 4 + w;
  int r0 = row_start[node];
  int r1 = row_start[node + 1];
  float acc = 0.f;
  for (int e = r0 + lane; e < r1; e += 64) acc += hs1[csr_src[e]];
#pragma unroll
  for (int off = 32; off; off >>= 1) acc += __shfl_xor(acc, off, 64);
  if (lane == 0) {
    float t = dinv[node] * (acc + hs1[node]) + b_out[0];
    g[node] = (t >= 0.f) ? t : NEG_SLOPE * t;
  }
}

// ---------------- FC head ----------------

__global__ __launch_bounds__(128) void k_fc1(const float* __restrict__ g,
                                             const float* __restrict__ fc1_W,
                                             float* __restrict__ h128) {
  int j = threadIdx.x;  // 0..127
  int base = blockIdx.x * 32;
  int end = base + 32;
  if (end > N_NODES) end = N_NODES;
  float acc = 0.f;
  int i = base;
  for (; i + 4 <= end; i += 4) {
    acc += g[i + 0] * fc1_W[(size_t)(i + 0) * 128 + j];
    acc += g[i + 1] * fc1_W[(size_t)(i + 1) * 128 + j];
    acc += g[i + 2] * fc1_W[(size_t)(i + 2) * 128 + j];
    acc += g[i + 3] * fc1_W[(size_t)(i + 3) * 128 + j];
  }
  for (; i < end; i++) acc += g[i] * fc1_W[(size_t)i * 128 + j];
  atomicAdd(&h128[j], acc);
}

__global__ __launch_bounds__(256) void k_fc2(const float* __restrict__ h128raw,
                                             const float* __restrict__ fc1_b,
                                             const float* __restrict__ fc2_W,
                                             const float* __restrict__ fc2_b,
                                             float* __restrict__ out) {
  __shared__ float sh[128];
  int tid = threadIdx.x;
  if (tid < 128) {
    float v = h128raw[tid] + fc1_b[tid];
    sh[tid] = (v > 0.f) ? v : 0.f;
  }
  __syncthreads();
  int p = blockIdx.x * 256 + tid;
  if (p < POI_LEN) {
    float acc = fc2_b[p];
#pragma unroll 8
    for (int j = 0; j < 128; j++) acc += sh[j] * fc2_W[(size_t)j * POI_LEN + p];
    out[p] = (acc > 0.f) ? acc : 0.f;
  }
}

// ---------------- launch ----------------

extern "C" void kernel_launch(void* const* d_in, const int* in_sizes, int n_in,
                              void* d_out, int out_size, void* d_ws, size_t ws_size,
                              hipStream_t stream) {
  const float* x       = (const float*)d_in[0];
  const int*   ei      = (const int*)d_in[1];
  const float* poi_emb = (const float*)d_in[2];
  const float* cat_emb = (const float*)d_in[3];
  const float* W_in    = (const float*)d_in[4];
  const float* b_in    = (const float*)d_in[5];
  const float* gcn_Ws  = (const float*)d_in[6];
  const float* gcn_bs  = (const float*)d_in[7];
  const float* W_out   = (const float*)d_in[8];
  const float* b_out   = (const float*)d_in[9];
  const float* fc1_W   = (const float*)d_in[10];
  const float* fc1_b   = (const float*)d_in[11];
  const float* fc2_W   = (const float*)d_in[12];
  const float* fc2_b   = (const float*)d_in[13];
  const int* src = ei;
  const int* dst = ei + N_EDGES;

  char* p = (char*)d_ws;
  auto take = [&](size_t bytes) {
    char* r = p;
    p += (bytes + 255) & ~(size_t)255;
    return r;
  };
  int*   cnt       = (int*)take((size_t)N_NODES * 4);
  int*   row_start = (int*)take((size_t)(N_NODES + 1) * 4);
  float* dinv      = (float*)take((size_t)N_NODES * 4);
  int*   bcur      = (int*)take((size_t)B1 * 4);
  int*   csr_src   = (int*)take((size_t)N_EDGES * 4);
  float* feat      = (float*)take((size_t)N_NODES * 64 * 4);
  float* hs        = (float*)take((size_t)N_NODES * 64 * 4);
  float* proj_poi  = (float*)take((size_t)POI_LEN * 64 * 4);  // aliased by staging
  float* proj_cat  = (float*)take((size_t)CAT_LEN * 64 * 4);
  float* hs1       = (float*)take((size_t)N_NODES * 4);
  float* g         = (float*)take((size_t)N_NODES * 4);
  float* h128      = (float*)take(128 * 4);
  int*   partial   = (int*)take((size_t)N_CHUNKS * 4);
  int2*  staging   = (int2*)proj_poi;  // both ~9.81 MB
  float* out       = (float*)d_out;

  const int nb4 = N_NODES / 4;            // 9583
  const int nbE = (N_EDGES + 255) / 256;  // 4792

  k_zero<<<N_CHUNKS, 256, 0, stream>>>(cnt, h128);
  k_count<<<nbE, 256, 0, stream>>>(dst, cnt);
  k_scan1<<<N_CHUNKS, 256, 0, stream>>>(cnt, partial, dinv);
  k_scan2<<<1, 256, 0, stream>>>(partial);
  k_scan3<<<N_CHUNKS, 256, 0, stream>>>(cnt, partial, row_start);
  k_binit<<<(B1 + 255) / 256, 256, 0, stream>>>(row_start, bcur);

  // front-end first (proj_poi's region is reused as scatter staging afterwards)
  k_proj<<<(POI_LEN + 15) / 16, 256, 0, stream>>>(poi_emb, W_in, proj_poi,
                                                  POI_LEN, POI_DIM);
  k_proj<<<(CAT_LEN + 15) / 16, 256, 0, stream>>>(cat_emb, W_in + 300 * 64,
                                                  proj_cat, CAT_LEN, CAT_DIM);
  k_gather<<<nb4, 256, 0, stream>>>(x, proj_poi, proj_cat, W_in, dinv, hs);

  // CSR edge placement (two-level, coalesced writes)
  k_split<<<NSPLIT, 256, 0, stream>>>(src, dst, bcur, staging);
  k_place<<<B1, 256, 0, stream>>>(staging, row_start, csr_src);

  k_agg<0><<<nb4, 256, 0, stream>>>(hs, row_start, csr_src, dinv, b_in, feat);
  for (int l = 0; l < 5; l++) {
    k_xform<<<nb4, 256, 0, stream>>>(feat, gcn_Ws + (size_t)l * 64 * 64, dinv, hs);
    k_agg<1><<<nb4, 256, 0, stream>>>(hs, row_start, csr_src, dinv,
                                      gcn_bs + (size_t)l * 64, feat);
  }

  k_out_xform<<<nb4, 256, 0, stream>>>(feat, W_out, dinv, hs1);
  k_out_agg<<<nb4, 256, 0, stream>>>(hs1, row_start, csr_src, dinv, b_out, g);
  k_fc1<<<(N_NODES + 31) / 32, 128, 0, stream>>>(g, fc1_W, h128);
  k_fc2<<<(POI_LEN + 255) / 256, 256, 0, stream>>>(h128, fc1_b, fc2_W, fc2_b, out);
}